// Round 10
// baseline (327.302 us; speedup 1.0000x reference)
//
#include <hip/hip_runtime.h>

typedef short bf16x8 __attribute__((ext_vector_type(8)));
typedef float f32x4 __attribute__((ext_vector_type(4)));
typedef float f32x16 __attribute__((ext_vector_type(16)));
using u16 = unsigned short;
using u32 = unsigned int;

#define MFMA_BF16(A, B, C) __builtin_amdgcn_mfma_f32_16x16x32_bf16((A), (B), (C), 0, 0, 0)
#define MFMA32_BF16(A, B, C) __builtin_amdgcn_mfma_f32_32x32x16_bf16((A), (B), (C), 0, 0, 0)

#define CC 256
#define DD 256
#define KK 8192
#define NN 16384     // B*H*W
#define HW 1024      // H*W
#define OUT0 4194304 // B*D*H*W
#define KSPLIT 16
#define KROWS 32     // k-rows (codes) per LDS tile (verified best)

static __device__ __forceinline__ float b2f(u16 u) {
    union { u32 i; float f; } v; v.i = ((u32)u) << 16; return v.f;
}
static __device__ __forceinline__ u16 f2b(float f) {  // RNE fp32 -> bf16
    union { float f; u32 i; } v; v.f = f;
    u32 x = v.i;
    u32 r = (x + 0x7fffu + ((x >> 16) & 1u)) >> 16;
    return (u16)r;
}
static __device__ __forceinline__ u32 f2u(float f) {
    union { float f; u32 u; } v; v.f = f; return v.u;
}
static __device__ __forceinline__ void split3(float v, u16& h, u16& m, u16& l) {
    h = f2b(v); float r1 = v - b2f(h);
    m = f2b(r1); float r2 = r1 - b2f(m);
    l = f2b(r2);
}

typedef __attribute__((address_space(1))) const u32 GlbU32;
typedef __attribute__((address_space(3))) u32 LdsU32;
static __device__ __forceinline__ void async_load16(const void* g, void* l) {
    __builtin_amdgcn_global_load_lds((GlbU32*)g, (LdsU32*)l, 16, 0, 0);
}

// ---------------------------------------------------------------------------
// K0 (fused prep): blocks [0,2048): transpose cb -> cbT fp32 + cbTh bf16;
// blocks [2048,2304): negC0[k] = -0.5*(||c_k||^2 + 1024);
// blocks [2304,2560): 3-way bf16 split of conv_w.
__global__ __launch_bounds__(256) void k_prep(const float* __restrict__ cb,
                                              const float* __restrict__ Wm,
                                              float* __restrict__ cbT,
                                              u16* __restrict__ cbTh,
                                              float* __restrict__ negC0,
                                              u16* __restrict__ wh,
                                              u16* __restrict__ wm,
                                              u16* __restrict__ wl) {
    int bx = blockIdx.x, tid = threadIdx.x;
    if (bx < 2048) {
        __shared__ float tile[32][33];
        int k0 = (bx & 255) * 32, d0 = (bx >> 8) * 32;
        int tx = tid & 31, ty = tid >> 5;  // 32 x 8
#pragma unroll
        for (int i = 0; i < 4; i++) {
            int d = d0 + ty + i * 8;
            tile[ty + i * 8][tx] = cb[d * KK + k0 + tx];
        }
        __syncthreads();
#pragma unroll
        for (int i = 0; i < 4; i++) {
            int k = k0 + ty + i * 8;
            float v = tile[tx][ty + i * 8];
            cbT[k * DD + d0 + tx] = v;
            cbTh[k * DD + d0 + tx] = f2b(v);
        }
    } else if (bx < 2304) {
        __shared__ float sm[8][32];
        int kl = tid & 31, dg = tid >> 5;
        int k = (bx - 2048) * 32 + kl;
        float s = 0.f;
#pragma unroll
        for (int j = 0; j < 32; j++) {
            float v = cb[(size_t)(dg * 32 + j) * KK + k];
            s += v * v;
        }
        sm[dg][kl] = s;
        __syncthreads();
        if (tid < 32) {
            float t = 0.f;
#pragma unroll
            for (int g = 0; g < 8; g++) t += sm[g][tid];
            negC0[(bx - 2048) * 32 + tid] = -0.5f * (t + 1024.f);
        }
    } else {
        int t = (bx - 2304) * 256 + tid;
        u16 h, m, l; split3(Wm[t], h, m, l);
        wh[t] = h; wm[t] = m; wl[t] = l;
    }
}

// ---------------------------------------------------------------------------
// K1: xp = x_r @ W^T + b via bf16x3 split MFMA (6 terms ~ fp32 accuracy).
__global__ __launch_bounds__(256) void k_proj(const float* __restrict__ x,
                                              const u16* __restrict__ wh,
                                              const u16* __restrict__ wm,
                                              const u16* __restrict__ wl,
                                              const float* __restrict__ bias,
                                              float* __restrict__ xp,
                                              u16* __restrict__ xpH) {
    int tid = threadIdx.x;
    int wave = tid >> 6, lane = tid & 63;
    int quad = lane >> 4, l15 = lane & 15;
    int rw = wave >> 1, dh = wave & 1;       // row-group / dt-half
    int n0 = blockIdx.x * 32 + rw * 16;
    int n_a = n0 + l15;
    const float* xb = x + (n_a >> 10) * (CC * HW) + (n_a & (HW - 1));

    f32x4 acc[8];
#pragma unroll
    for (int i = 0; i < 8; i++) acc[i] = (f32x4){0.f, 0.f, 0.f, 0.f};

#pragma unroll
    for (int cc = 0; cc < 8; cc++) {
        bf16x8 ah, am, al;
#pragma unroll
        for (int j = 0; j < 8; j++) {
            float v = xb[(cc * 32 + quad * 8 + j) * HW];
            u16 h, m, l; split3(v, h, m, l);
            ah[j] = (short)h; am[j] = (short)m; al[j] = (short)l;
        }
#pragma unroll
        for (int dt = 0; dt < 8; dt++) {
            int dtg = dh * 8 + dt;
            int off = (dtg * 16 + l15) * CC + cc * 32 + quad * 8;
            const bf16x8 bh = *(const bf16x8*)(wh + off);
            const bf16x8 bm = *(const bf16x8*)(wm + off);
            const bf16x8 bl = *(const bf16x8*)(wl + off);
            acc[dt] = MFMA_BF16(ah, bh, acc[dt]);
            acc[dt] = MFMA_BF16(am, bh, acc[dt]);
            acc[dt] = MFMA_BF16(ah, bm, acc[dt]);
            acc[dt] = MFMA_BF16(al, bh, acc[dt]);
            acc[dt] = MFMA_BF16(am, bm, acc[dt]);
            acc[dt] = MFMA_BF16(ah, bl, acc[dt]);
        }
    }

#pragma unroll
    for (int dt = 0; dt < 8; dt++) {
        int d = (dh * 8 + dt) * 16 + l15;   // C-layout: col = lane&15
        float bv = bias[d];
#pragma unroll
        for (int r = 0; r < 4; r++) {
            int n = n0 + quad * 4 + r;      // C-layout: row = quad*4 + reg
            float v = acc[dt][r] + bv;
            xp[n * DD + d] = v;
            xpH[n * DD + d] = f2b(v);
        }
    }
}

// ---------------------------------------------------------------------------
// K2: approx distance GEMM (32x32x16 MFMA) + fused argmin-candidate select.
// Verified best structure (R1: 92.6 us): KROWS=32, XOR swizzle, 2 LDS
// buffers, __syncthreads per kc, mt=1, ILP-2 MFMA chains. Single dispatch
// (R9's 2-way split cost ~6 us in launch/tail overhead).
// C/D (verified m74/m101): col = lane&31, row = (reg&3)+8*(reg>>2)+4*(lane>>5).
__global__ __launch_bounds__(256, 3) void k_dist(const u16* __restrict__ xpH,
                                                 const u16* __restrict__ cbTh,
                                                 const float* __restrict__ negC0,
                                                 u32* __restrict__ pkey) {
    __shared__ __align__(16) u16 tile[2][KROWS * 256];  // 2 x 16 KB
    int tid = threadIdx.x, wave = tid >> 6, lane = tid & 63;
    int col = lane & 31, half = lane >> 5;
    int n0 = blockIdx.x * 128 + wave * 32;
    int ksbase = blockIdx.y * (KK / KSPLIT);   // 512 codes per split

    // A-frags resident: 16 ks (row = col, dims ks*16 + half*8 + j)
    bf16x8 Ah[16];
    {
        const u16* ab = xpH + (size_t)(n0 + col) * DD + half * 8;
#pragma unroll
        for (int ks = 0; ks < 16; ks++)
            Ah[ks] = *(const bf16x8*)(ab + ks * 16);
    }

    u32 key[16];
#pragma unroll
    for (int g = 0; g < 16; g++) key[g] = 0xffffffffu;

#define STAGE(bufi, kglob_)                                                    \
    {                                                                          \
        int kg_ = (kglob_);                                                    \
        _Pragma("unroll")                                                      \
        for (int c = 0; c < 4; c++) {                                          \
            int chunk = wave * 4 + c;                                          \
            int row = chunk * 2 + (lane >> 5);                                 \
            int g = (lane & 31) ^ (row & 7);                                   \
            const u16* src = cbTh + (size_t)(kg_ + row) * DD + g * 8;          \
            async_load16(src, &tile[bufi][chunk * 512]);                       \
        }                                                                      \
    }

    STAGE(0, ksbase);
    float nc_cur = negC0[ksbase + col];
    __syncthreads();

    for (int kc = 0; kc < 16; kc++) {
        int buf = kc & 1;
        float nc_next = 0.f;
        if (kc < 15) {
            STAGE(buf ^ 1, ksbase + (kc + 1) * KROWS);
            nc_next = negC0[ksbase + (kc + 1) * KROWS + col];
        }

        f32x16 a0, a1;
#pragma unroll
        for (int g = 0; g < 16; g++) { a0[g] = nc_cur; a1[g] = 0.f; }

        const u16* trow = &tile[buf][col * 256];
#pragma unroll
        for (int ks = 0; ks < 8; ks++) {
            int g0 = ((2 * ks) * 2 + half) ^ (col & 7);
            int g1 = ((2 * ks + 1) * 2 + half) ^ (col & 7);
            const bf16x8 Bf0 = *(const bf16x8*)(trow + g0 * 8);
            const bf16x8 Bf1 = *(const bf16x8*)(trow + g1 * 8);
            a0 = MFMA32_BF16(Ah[2 * ks], Bf0, a0);
            a1 = MFMA32_BF16(Ah[2 * ks + 1], Bf1, a1);
        }

        u32 orv = ((u32)kc << 5) | (u32)col;
#pragma unroll
        for (int g = 0; g < 16; g++) {
            u32 kb = (f2u(a0[g] + a1[g]) & 0xFFFFFE00u) | orv;
            key[g] = min(key[g], kb);
        }
        nc_cur = nc_next;
        __syncthreads();  // drains prefetch + guards buffers
    }
#undef STAGE

    // top-2 across the 32 lanes (cols) sharing each C row
#pragma unroll
    for (int g = 0; g < 16; g++) {
        u32 k1 = key[g], k2 = 0xffffffffu;
#pragma unroll
        for (int m = 1; m < 32; m <<= 1) {
            u32 o1 = (u32)__shfl_xor((int)k1, m, 64);
            u32 o2 = (u32)__shfl_xor((int)k2, m, 64);
            u32 mx = max(k1, o1);
            k1 = min(k1, o1);
            k2 = min(min(k2, o2), mx);
        }
        if (col == 0) {
            int row = (g & 3) + 8 * (g >> 2) + 4 * half;
            int n = n0 + row;
            int base = (n * KSPLIT + blockIdx.y) * 2;
            pkey[base]     = (u32)ksbase + (k1 & 511u);
            pkey[base + 1] = (u32)ksbase + (k2 & 511u);
        }
    }
}

// ---------------------------------------------------------------------------
// K3: exact fp64 rescore of 32 candidates per row.
// R10: TLP restructure — ONE BLOCK (4 waves) PER ROW, one candidate-group per
// wave (was: 1 wave/row, 4 serial groups). Serial gather->reduce chain depth
// drops 4x; wave pool 16k -> 64k (64/SIMD queued) hides the ~600-900 cyc
// gather latency via TLP (R8 showed ILP+VGPR does NOT work here; R9 counters
// showed pure latency-bound: VALUBusy 17.7%, FETCH 47MB, nothing saturated).
// Comparator is a total order (min, tie-break smaller index) -> reduction
// order change is result-identical.
__global__ __launch_bounds__(256) void k_rescore(const float* __restrict__ xp,
                                                 const float* __restrict__ cbT,
                                                 const u32* __restrict__ pkey,
                                                 u32* __restrict__ idxv,
                                                 float* __restrict__ outIdx,
                                                 float* __restrict__ pmin) {
    __shared__ double sbv[4];
    __shared__ u32 sbi[4];
    int tid = threadIdx.x, wave = tid >> 6, lane = tid & 63;
    int n = blockIdx.x;
    int sub = lane >> 3;
    int oct = lane & 7;

    f32x4 xv[8];
    const float* xb = xp + n * DD + oct * 32;
#pragma unroll
    for (int t = 0; t < 8; t++) xv[t] = *(const f32x4*)(xb + t * 4);

    // this wave's candidate for this subgroup (8 lanes share one candidate;
    // same address across the 8 lanes -> broadcast load)
    u32 kg = pkey[n * 32 + wave * 8 + sub] & 8191u;

    const float* cv = cbT + (size_t)kg * DD + oct * 32;
    double s = 0.0;
#pragma unroll
    for (int t = 0; t < 8; t++) {
        f32x4 cvv = *(const f32x4*)(cv + t * 4);
#pragma unroll
        for (int q = 0; q < 4; q++) {
            double d = (double)xv[t][q] - (double)cvv[q];
            s += d * d;
        }
    }
    s += __shfl_xor(s, 1, 64);
    s += __shfl_xor(s, 2, 64);
    s += __shfl_xor(s, 4, 64);

    double bestv = s;
    u32 besti = kg;
#pragma unroll
    for (int m = 8; m < 64; m <<= 1) {
        double ov = __shfl_xor(bestv, m, 64);
        u32 oi = (u32)__shfl_xor((int)besti, m, 64);
        if (ov < bestv || (ov == bestv && oi < besti)) { bestv = ov; besti = oi; }
    }
    if (lane == 0) { sbv[wave] = bestv; sbi[wave] = besti; }
    __syncthreads();
    if (tid == 0) {
        double bv = sbv[0]; u32 bi = sbi[0];
#pragma unroll
        for (int wv = 1; wv < 4; wv++) {
            double ov = sbv[wv]; u32 oi = sbi[wv];
            if (ov < bv || (ov == bv && oi < bi)) { bv = ov; bi = oi; }
        }
        idxv[n] = bi;
        outIdx[n] = (float)bi;
        pmin[n] = (float)bv;
    }
}

// ---------------------------------------------------------------------------
// K4: diff = sum(pmin)/(N*D), fp64 (pmin in ws, no ordering constraint).
__global__ __launch_bounds__(1024) void k_final(const float* __restrict__ pmin,
                                                float* __restrict__ out) {
    __shared__ double sm[16];
    int tid = threadIdx.x, lane = tid & 63, wv = tid >> 6;
    double s = 0.0;
#pragma unroll
    for (int i = 0; i < 16; i++) s += (double)pmin[i * 1024 + tid];
#pragma unroll
    for (int m = 1; m < 64; m <<= 1) s += __shfl_xor(s, m, 64);
    if (lane == 0) sm[wv] = s;
    __syncthreads();
    if (tid == 0) {
        double t = 0.0;
#pragma unroll
        for (int i = 0; i < 16; i++) t += sm[i];
        out[0] = (float)(t * (1.0 / (double)OUT0));
    }
}

// ---------------------------------------------------------------------------
// K5: gather quantized (B,D,H,W) fp32 via LDS transpose tiles. Rewrites ALL
// of d_out chunk 0 (every scratch byte).
__global__ __launch_bounds__(256) void k_gather(const float* __restrict__ cbT,
                                                const u32* __restrict__ idxv,
                                                float* __restrict__ out0) {
    __shared__ float tile[32 * 260];
    int tid = threadIdx.x;
    int n0 = blockIdx.x * 32;
    int b = n0 >> 10, hw0 = n0 & 1023;

    {
        int r = tid >> 3, seg = tid & 7;
        u32 k = idxv[n0 + r] & 8191u;
        const float* src = cbT + k * DD + seg * 32;
        float* dst = tile + r * 260 + seg * 32;
#pragma unroll
        for (int j = 0; j < 8; j++)
            *(f32x4*)(dst + j * 4) = *(const f32x4*)(src + j * 4);
    }
    __syncthreads();
    {
        int hw = tid & 31, dq = tid >> 5;
        const float* trow = tile + hw * 260;
        float* obase = out0 + ((size_t)b * DD) * HW + hw0 + hw;
#pragma unroll
        for (int dj = 0; dj < 32; dj++) {
            int d = dq * 32 + dj;
            obase[(size_t)d * HW] = trow[d];
        }
    }
}

// ---------------------------------------------------------------------------
extern "C" void kernel_launch(void* const* d_in, const int* in_sizes, int n_in,
                              void* d_out, int out_size, void* d_ws, size_t ws_size,
                              hipStream_t stream) {
    const float* x = nullptr; const float* Wm = nullptr;
    const float* bias = nullptr; const float* cb = nullptr;
    for (int i = 0; i < n_in; i++) {
        switch (in_sizes[i]) {
            case 4194304: x    = (const float*)d_in[i]; break;  // (16,256,32,32)
            case 65536:   Wm   = (const float*)d_in[i]; break;  // (256,256)
            case 256:     bias = (const float*)d_in[i]; break;  // (256,)
            case 2097152: cb   = (const float*)d_in[i]; break;  // (256,8192)
        }
    }

    // d_out is FP32: [quantized (4194304) | diff (1) | indices (16384)]
    float* out0    = (float*)d_out;
    float* outDiff = (float*)d_out + OUT0;
    float* outIdx  = (float*)d_out + OUT0 + 1;

    // Transient scratch inside d_out chunk 0 (16.78 MB; every byte rewritten
    // by k_gather before the harness reads):
    char* o = (char*)d_out;
    u16*   cbTh = (u16*)o;                       // [0, 4 MB)
    u32*   pkey = (u32*)(o + 4194304);           // [4 MB, 6 MB)
    u16*   wh   = (u16*)(o + 6291456);           // 128 KB
    u16*   wm   = (u16*)(o + 6422528);           // 128 KB
    u16*   wl   = (u16*)(o + 6553600);           // 128 KB
    u16*   xpH  = (u16*)(o + 6750208);           // 8 MB  (N,D) bf16 -> ends 14.75 MB

    // Workspace (~25.33 MB, footprint that passed in rounds 4-9):
    char* w = (char*)d_ws;
    float* cbT   = (float*)(w);                  // 8 MB  (K,D) fp32
    float* xp    = (float*)(w + 8388608);        // 16 MB (N,D) fp32
    float* negC0 = (float*)(w + 25165824);       // 32 KB
    u32*   idxv  = (u32*)(w + 25198592);         // 64 KB
    float* pmin  = (float*)(w + 25264128);       // 64 KB

    k_prep<<<2560, 256, 0, stream>>>(cb, Wm, cbT, cbTh, negC0, wh, wm, wl);
    k_proj<<<NN / 32, 256, 0, stream>>>(x, wh, wm, wl, bias, xp, xpH);
    k_dist<<<dim3(NN / 128, KSPLIT), 256, 0, stream>>>(xpH, cbTh, negC0, pkey);
    k_rescore<<<NN, 256, 0, stream>>>(xp, cbT, pkey, idxv, outIdx, pmin);
    k_final<<<1, 1024, 0, stream>>>(pmin, outDiff);
    k_gather<<<NN / 32, 256, 0, stream>>>(cbT, idxv, out0);
}

// Round 11
// 311.693 us; speedup vs baseline: 1.0501x; 1.0501x over previous
//
#include <hip/hip_runtime.h>

typedef short bf16x8 __attribute__((ext_vector_type(8)));
typedef float f32x4 __attribute__((ext_vector_type(4)));
typedef float f32x16 __attribute__((ext_vector_type(16)));
using u16 = unsigned short;
using u32 = unsigned int;

#define MFMA_BF16(A, B, C) __builtin_amdgcn_mfma_f32_16x16x32_bf16((A), (B), (C), 0, 0, 0)
#define MFMA32_BF16(A, B, C) __builtin_amdgcn_mfma_f32_32x32x16_bf16((A), (B), (C), 0, 0, 0)

#define CC 256
#define DD 256
#define KK 8192
#define NN 16384     // B*H*W
#define HW 1024      // H*W
#define OUT0 4194304 // B*D*H*W
#define KSPLIT 16
#define KROWS 32     // k-rows (codes) per LDS tile (verified best)

static __device__ __forceinline__ float b2f(u16 u) {
    union { u32 i; float f; } v; v.i = ((u32)u) << 16; return v.f;
}
static __device__ __forceinline__ u16 f2b(float f) {  // RNE fp32 -> bf16
    union { float f; u32 i; } v; v.f = f;
    u32 x = v.i;
    u32 r = (x + 0x7fffu + ((x >> 16) & 1u)) >> 16;
    return (u16)r;
}
static __device__ __forceinline__ u32 f2u(float f) {
    union { float f; u32 u; } v; v.f = f; return v.u;
}
static __device__ __forceinline__ void split3(float v, u16& h, u16& m, u16& l) {
    h = f2b(v); float r1 = v - b2f(h);
    m = f2b(r1); float r2 = r1 - b2f(m);
    l = f2b(r2);
}

typedef __attribute__((address_space(1))) const u32 GlbU32;
typedef __attribute__((address_space(3))) u32 LdsU32;
static __device__ __forceinline__ void async_load16(const void* g, void* l) {
    __builtin_amdgcn_global_load_lds((GlbU32*)g, (LdsU32*)l, 16, 0, 0);
}

// ---------------------------------------------------------------------------
// K0 (fused prep): blocks [0,2048): transpose cb -> cbT fp32 + cbTh bf16;
// blocks [2048,2304): negC0[k] = -0.5*(||c_k||^2 + 1024);
// blocks [2304,2560): 3-way bf16 split of conv_w.
__global__ __launch_bounds__(256) void k_prep(const float* __restrict__ cb,
                                              const float* __restrict__ Wm,
                                              float* __restrict__ cbT,
                                              u16* __restrict__ cbTh,
                                              float* __restrict__ negC0,
                                              u16* __restrict__ wh,
                                              u16* __restrict__ wm,
                                              u16* __restrict__ wl) {
    int bx = blockIdx.x, tid = threadIdx.x;
    if (bx < 2048) {
        __shared__ float tile[32][33];
        int k0 = (bx & 255) * 32, d0 = (bx >> 8) * 32;
        int tx = tid & 31, ty = tid >> 5;  // 32 x 8
#pragma unroll
        for (int i = 0; i < 4; i++) {
            int d = d0 + ty + i * 8;
            tile[ty + i * 8][tx] = cb[d * KK + k0 + tx];
        }
        __syncthreads();
#pragma unroll
        for (int i = 0; i < 4; i++) {
            int k = k0 + ty + i * 8;
            float v = tile[tx][ty + i * 8];
            cbT[k * DD + d0 + tx] = v;
            cbTh[k * DD + d0 + tx] = f2b(v);
        }
    } else if (bx < 2304) {
        __shared__ float sm[8][32];
        int kl = tid & 31, dg = tid >> 5;
        int k = (bx - 2048) * 32 + kl;
        float s = 0.f;
#pragma unroll
        for (int j = 0; j < 32; j++) {
            float v = cb[(size_t)(dg * 32 + j) * KK + k];
            s += v * v;
        }
        sm[dg][kl] = s;
        __syncthreads();
        if (tid < 32) {
            float t = 0.f;
#pragma unroll
            for (int g = 0; g < 8; g++) t += sm[g][tid];
            negC0[(bx - 2048) * 32 + tid] = -0.5f * (t + 1024.f);
        }
    } else {
        int t = (bx - 2304) * 256 + tid;
        u16 h, m, l; split3(Wm[t], h, m, l);
        wh[t] = h; wm[t] = m; wl[t] = l;
    }
}

// ---------------------------------------------------------------------------
// K1: xp = x_r @ W^T + b via bf16x3 split MFMA (6 terms ~ fp32 accuracy).
__global__ __launch_bounds__(256) void k_proj(const float* __restrict__ x,
                                              const u16* __restrict__ wh,
                                              const u16* __restrict__ wm,
                                              const u16* __restrict__ wl,
                                              const float* __restrict__ bias,
                                              float* __restrict__ xp,
                                              u16* __restrict__ xpH) {
    int tid = threadIdx.x;
    int wave = tid >> 6, lane = tid & 63;
    int quad = lane >> 4, l15 = lane & 15;
    int rw = wave >> 1, dh = wave & 1;       // row-group / dt-half
    int n0 = blockIdx.x * 32 + rw * 16;
    int n_a = n0 + l15;
    const float* xb = x + (n_a >> 10) * (CC * HW) + (n_a & (HW - 1));

    f32x4 acc[8];
#pragma unroll
    for (int i = 0; i < 8; i++) acc[i] = (f32x4){0.f, 0.f, 0.f, 0.f};

#pragma unroll
    for (int cc = 0; cc < 8; cc++) {
        bf16x8 ah, am, al;
#pragma unroll
        for (int j = 0; j < 8; j++) {
            float v = xb[(cc * 32 + quad * 8 + j) * HW];
            u16 h, m, l; split3(v, h, m, l);
            ah[j] = (short)h; am[j] = (short)m; al[j] = (short)l;
        }
#pragma unroll
        for (int dt = 0; dt < 8; dt++) {
            int dtg = dh * 8 + dt;
            int off = (dtg * 16 + l15) * CC + cc * 32 + quad * 8;
            const bf16x8 bh = *(const bf16x8*)(wh + off);
            const bf16x8 bm = *(const bf16x8*)(wm + off);
            const bf16x8 bl = *(const bf16x8*)(wl + off);
            acc[dt] = MFMA_BF16(ah, bh, acc[dt]);
            acc[dt] = MFMA_BF16(am, bh, acc[dt]);
            acc[dt] = MFMA_BF16(ah, bm, acc[dt]);
            acc[dt] = MFMA_BF16(al, bh, acc[dt]);
            acc[dt] = MFMA_BF16(am, bm, acc[dt]);
            acc[dt] = MFMA_BF16(ah, bl, acc[dt]);
        }
    }

#pragma unroll
    for (int dt = 0; dt < 8; dt++) {
        int d = (dh * 8 + dt) * 16 + l15;   // C-layout: col = lane&15
        float bv = bias[d];
#pragma unroll
        for (int r = 0; r < 4; r++) {
            int n = n0 + quad * 4 + r;      // C-layout: row = quad*4 + reg
            float v = acc[dt][r] + bv;
            xp[n * DD + d] = v;
            xpH[n * DD + d] = f2b(v);
        }
    }
}

// ---------------------------------------------------------------------------
// K2: approx distance GEMM (32x32x16 MFMA) + fused argmin-candidate select.
// Verified best structure (R1: 92.6 us total at full grid): KROWS=32, XOR
// swizzle, 2 LDS buffers, __syncthreads per kc, mt=1, ILP-2 MFMA chains.
// R11: dispatched as 4 y-chunks (yoff = 0,4,8,12) purely to lower the
// rocprof top-5 duration filter (~24 us) — measurement round.
// C/D (verified m74/m101): col = lane&31, row = (reg&3)+8*(reg>>2)+4*(lane>>5).
__global__ __launch_bounds__(256, 3) void k_dist(const u16* __restrict__ xpH,
                                                 const u16* __restrict__ cbTh,
                                                 const float* __restrict__ negC0,
                                                 u32* __restrict__ pkey,
                                                 int yoff) {
    __shared__ __align__(16) u16 tile[2][KROWS * 256];  // 2 x 16 KB
    int tid = threadIdx.x, wave = tid >> 6, lane = tid & 63;
    int col = lane & 31, half = lane >> 5;
    int n0 = blockIdx.x * 128 + wave * 32;
    int ysplit = blockIdx.y + yoff;
    int ksbase = ysplit * (KK / KSPLIT);   // 512 codes per split

    // A-frags resident: 16 ks (row = col, dims ks*16 + half*8 + j)
    bf16x8 Ah[16];
    {
        const u16* ab = xpH + (size_t)(n0 + col) * DD + half * 8;
#pragma unroll
        for (int ks = 0; ks < 16; ks++)
            Ah[ks] = *(const bf16x8*)(ab + ks * 16);
    }

    u32 key[16];
#pragma unroll
    for (int g = 0; g < 16; g++) key[g] = 0xffffffffu;

#define STAGE(bufi, kglob_)                                                    \
    {                                                                          \
        int kg_ = (kglob_);                                                    \
        _Pragma("unroll")                                                      \
        for (int c = 0; c < 4; c++) {                                          \
            int chunk = wave * 4 + c;                                          \
            int row = chunk * 2 + (lane >> 5);                                 \
            int g = (lane & 31) ^ (row & 7);                                   \
            const u16* src = cbTh + (size_t)(kg_ + row) * DD + g * 8;          \
            async_load16(src, &tile[bufi][chunk * 512]);                       \
        }                                                                      \
    }

    STAGE(0, ksbase);
    float nc_cur = negC0[ksbase + col];
    __syncthreads();

    for (int kc = 0; kc < 16; kc++) {
        int buf = kc & 1;
        float nc_next = 0.f;
        if (kc < 15) {
            STAGE(buf ^ 1, ksbase + (kc + 1) * KROWS);
            nc_next = negC0[ksbase + (kc + 1) * KROWS + col];
        }

        f32x16 a0, a1;
#pragma unroll
        for (int g = 0; g < 16; g++) { a0[g] = nc_cur; a1[g] = 0.f; }

        const u16* trow = &tile[buf][col * 256];
#pragma unroll
        for (int ks = 0; ks < 8; ks++) {
            int g0 = ((2 * ks) * 2 + half) ^ (col & 7);
            int g1 = ((2 * ks + 1) * 2 + half) ^ (col & 7);
            const bf16x8 Bf0 = *(const bf16x8*)(trow + g0 * 8);
            const bf16x8 Bf1 = *(const bf16x8*)(trow + g1 * 8);
            a0 = MFMA32_BF16(Ah[2 * ks], Bf0, a0);
            a1 = MFMA32_BF16(Ah[2 * ks + 1], Bf1, a1);
        }

        u32 orv = ((u32)kc << 5) | (u32)col;
#pragma unroll
        for (int g = 0; g < 16; g++) {
            u32 kb = (f2u(a0[g] + a1[g]) & 0xFFFFFE00u) | orv;
            key[g] = min(key[g], kb);
        }
        nc_cur = nc_next;
        __syncthreads();  // drains prefetch + guards buffers
    }
#undef STAGE

    // top-2 across the 32 lanes (cols) sharing each C row
#pragma unroll
    for (int g = 0; g < 16; g++) {
        u32 k1 = key[g], k2 = 0xffffffffu;
#pragma unroll
        for (int m = 1; m < 32; m <<= 1) {
            u32 o1 = (u32)__shfl_xor((int)k1, m, 64);
            u32 o2 = (u32)__shfl_xor((int)k2, m, 64);
            u32 mx = max(k1, o1);
            k1 = min(k1, o1);
            k2 = min(min(k2, o2), mx);
        }
        if (col == 0) {
            int row = (g & 3) + 8 * (g >> 2) + 4 * half;
            int n = n0 + row;
            int base = (n * KSPLIT + ysplit) * 2;
            pkey[base]     = (u32)ksbase + (k1 & 511u);
            pkey[base + 1] = (u32)ksbase + (k2 & 511u);
        }
    }
}

// ---------------------------------------------------------------------------
// K3: exact fp64 rescore of 32 candidates per row. One wave per row, 4 serial
// groups (verified best: 79 us at full grid — R8 ILP and R10 TLP variants
// both regressed; kernel is bound by scattered-request throughput).
// R11: dispatched as 4 row-chunks (noff) for the measurement round.
__global__ __launch_bounds__(256) void k_rescore(const float* __restrict__ xp,
                                                 const float* __restrict__ cbT,
                                                 const u32* __restrict__ pkey,
                                                 u32* __restrict__ idxv,
                                                 float* __restrict__ outIdx,
                                                 float* __restrict__ pmin,
                                                 int noff) {
    int tid = threadIdx.x, wave = tid >> 6, lane = tid & 63;
    int n = (blockIdx.x + noff) * 4 + wave;
    int sub = lane >> 3;
    int oct = lane & 7;

    f32x4 xv[8];
    const float* xb = xp + n * DD + oct * 32;
#pragma unroll
    for (int t = 0; t < 8; t++) xv[t] = *(const f32x4*)(xb + t * 4);

    u32 myk = pkey[n * 32 + (lane & 31)] & 8191u;

    double bestv = 1e300;
    u32 besti = 0u;
#pragma unroll
    for (int g = 0; g < 4; g++) {
        int c = g * 8 + sub;
        u32 kg = (u32)__shfl((int)myk, c, 64);
        const float* cv = cbT + kg * DD + oct * 32;
        double s = 0.0;
#pragma unroll
        for (int t = 0; t < 8; t++) {
            f32x4 cvv = *(const f32x4*)(cv + t * 4);
#pragma unroll
            for (int q = 0; q < 4; q++) {
                double d = (double)xv[t][q] - (double)cvv[q];
                s += d * d;
            }
        }
        s += __shfl_xor(s, 1, 64);
        s += __shfl_xor(s, 2, 64);
        s += __shfl_xor(s, 4, 64);
        if (s < bestv || (s == bestv && kg < besti)) { bestv = s; besti = kg; }
    }
#pragma unroll
    for (int m = 8; m < 64; m <<= 1) {
        double ov = __shfl_xor(bestv, m, 64);
        u32 oi = (u32)__shfl_xor((int)besti, m, 64);
        if (ov < bestv || (ov == bestv && oi < besti)) { bestv = ov; besti = oi; }
    }
    if (lane == 0) {
        idxv[n] = besti;
        outIdx[n] = (float)besti;
        pmin[n] = (float)bestv;
    }
}

// ---------------------------------------------------------------------------
// K4: diff = sum(pmin)/(N*D), fp64 (pmin in ws, no ordering constraint).
__global__ __launch_bounds__(1024) void k_final(const float* __restrict__ pmin,
                                                float* __restrict__ out) {
    __shared__ double sm[16];
    int tid = threadIdx.x, lane = tid & 63, wv = tid >> 6;
    double s = 0.0;
#pragma unroll
    for (int i = 0; i < 16; i++) s += (double)pmin[i * 1024 + tid];
#pragma unroll
    for (int m = 1; m < 64; m <<= 1) s += __shfl_xor(s, m, 64);
    if (lane == 0) sm[wv] = s;
    __syncthreads();
    if (tid == 0) {
        double t = 0.0;
#pragma unroll
        for (int i = 0; i < 16; i++) t += sm[i];
        out[0] = (float)(t * (1.0 / (double)OUT0));
    }
}

// ---------------------------------------------------------------------------
// K5: gather quantized (B,D,H,W) fp32 via LDS transpose tiles. Rewrites ALL
// of d_out chunk 0 (every scratch byte).
__global__ __launch_bounds__(256) void k_gather(const float* __restrict__ cbT,
                                                const u32* __restrict__ idxv,
                                                float* __restrict__ out0) {
    __shared__ float tile[32 * 260];
    int tid = threadIdx.x;
    int n0 = blockIdx.x * 32;
    int b = n0 >> 10, hw0 = n0 & 1023;

    {
        int r = tid >> 3, seg = tid & 7;
        u32 k = idxv[n0 + r] & 8191u;
        const float* src = cbT + k * DD + seg * 32;
        float* dst = tile + r * 260 + seg * 32;
#pragma unroll
        for (int j = 0; j < 8; j++)
            *(f32x4*)(dst + j * 4) = *(const f32x4*)(src + j * 4);
    }
    __syncthreads();
    {
        int hw = tid & 31, dq = tid >> 5;
        const float* trow = tile + hw * 260;
        float* obase = out0 + ((size_t)b * DD) * HW + hw0 + hw;
#pragma unroll
        for (int dj = 0; dj < 32; dj++) {
            int d = dq * 32 + dj;
            obase[(size_t)d * HW] = trow[d];
        }
    }
}

// ---------------------------------------------------------------------------
extern "C" void kernel_launch(void* const* d_in, const int* in_sizes, int n_in,
                              void* d_out, int out_size, void* d_ws, size_t ws_size,
                              hipStream_t stream) {
    const float* x = nullptr; const float* Wm = nullptr;
    const float* bias = nullptr; const float* cb = nullptr;
    for (int i = 0; i < n_in; i++) {
        switch (in_sizes[i]) {
            case 4194304: x    = (const float*)d_in[i]; break;  // (16,256,32,32)
            case 65536:   Wm   = (const float*)d_in[i]; break;  // (256,256)
            case 256:     bias = (const float*)d_in[i]; break;  // (256,)
            case 2097152: cb   = (const float*)d_in[i]; break;  // (256,8192)
        }
    }

    // d_out is FP32: [quantized (4194304) | diff (1) | indices (16384)]
    float* out0    = (float*)d_out;
    float* outDiff = (float*)d_out + OUT0;
    float* outIdx  = (float*)d_out + OUT0 + 1;

    // Transient scratch inside d_out chunk 0 (16.78 MB; every byte rewritten
    // by k_gather before the harness reads):
    char* o = (char*)d_out;
    u16*   cbTh = (u16*)o;                       // [0, 4 MB)
    u32*   pkey = (u32*)(o + 4194304);           // [4 MB, 6 MB)
    u16*   wh   = (u16*)(o + 6291456);           // 128 KB
    u16*   wm   = (u16*)(o + 6422528);           // 128 KB
    u16*   wl   = (u16*)(o + 6553600);           // 128 KB
    u16*   xpH  = (u16*)(o + 6750208);           // 8 MB  (N,D) bf16 -> ends 14.75 MB

    // Workspace (~25.33 MB, footprint that passed in rounds 4-9):
    char* w = (char*)d_ws;
    float* cbT   = (float*)(w);                  // 8 MB  (K,D) fp32
    float* xp    = (float*)(w + 8388608);        // 16 MB (N,D) fp32
    float* negC0 = (float*)(w + 25165824);       // 32 KB
    u32*   idxv  = (u32*)(w + 25198592);         // 64 KB
    float* pmin  = (float*)(w + 25264128);       // 64 KB

    k_prep<<<2560, 256, 0, stream>>>(cb, Wm, cbT, cbTh, negC0, wh, wm, wl);
    k_proj<<<NN / 32, 256, 0, stream>>>(x, wh, wm, wl, bias, xp, xpH);
    for (int yo = 0; yo < KSPLIT; yo += 4)
        k_dist<<<dim3(NN / 128, 4), 256, 0, stream>>>(xpH, cbTh, negC0, pkey, yo);
    for (int no = 0; no < NN / 4; no += 1024)
        k_rescore<<<1024, 256, 0, stream>>>(xp, cbT, pkey, idxv, outIdx, pmin, no);
    k_final<<<1, 1024, 0, stream>>>(pmin, outDiff);
    k_gather<<<NN / 32, 256, 0, stream>>>(cbT, idxv, out0);
}

// Round 12
// 286.932 us; speedup vs baseline: 1.1407x; 1.0863x over previous
//
#include <hip/hip_runtime.h>

typedef short bf16x8 __attribute__((ext_vector_type(8)));
typedef float f32x4 __attribute__((ext_vector_type(4)));
typedef float f32x16 __attribute__((ext_vector_type(16)));
using u16 = unsigned short;
using u32 = unsigned int;

#define MFMA_BF16(A, B, C) __builtin_amdgcn_mfma_f32_16x16x32_bf16((A), (B), (C), 0, 0, 0)
#define MFMA32_BF16(A, B, C) __builtin_amdgcn_mfma_f32_32x32x16_bf16((A), (B), (C), 0, 0, 0)

#define CC 256
#define DD 256
#define KK 8192
#define NN 16384     // B*H*W
#define HW 1024      // H*W
#define OUT0 4194304 // B*D*H*W
#define KSPLIT 16
#define KROWS 32     // k-rows (codes) per LDS tile (verified best)

static __device__ __forceinline__ float b2f(u16 u) {
    union { u32 i; float f; } v; v.i = ((u32)u) << 16; return v.f;
}
static __device__ __forceinline__ u16 f2b(float f) {  // RNE fp32 -> bf16
    union { float f; u32 i; } v; v.f = f;
    u32 x = v.i;
    u32 r = (x + 0x7fffu + ((x >> 16) & 1u)) >> 16;
    return (u16)r;
}
static __device__ __forceinline__ u32 f2u(float f) {
    union { float f; u32 u; } v; v.f = f; return v.u;
}
static __device__ __forceinline__ void split3(float v, u16& h, u16& m, u16& l) {
    h = f2b(v); float r1 = v - b2f(h);
    m = f2b(r1); float r2 = r1 - b2f(m);
    l = f2b(r2);
}

typedef __attribute__((address_space(1))) const u32 GlbU32;
typedef __attribute__((address_space(3))) u32 LdsU32;
static __device__ __forceinline__ void async_load16(const void* g, void* l) {
    __builtin_amdgcn_global_load_lds((GlbU32*)g, (LdsU32*)l, 16, 0, 0);
}

// ---------------------------------------------------------------------------
// K0 (fused prep): blocks [0,2048): transpose cb -> cbT fp32 + cbTh bf16;
// blocks [2048,2304): negC0[k] = -0.5*(||c_k||^2 + 1024);
// blocks [2304,2560): 3-way bf16 split of conv_w.
__global__ __launch_bounds__(256) void k_prep(const float* __restrict__ cb,
                                              const float* __restrict__ Wm,
                                              float* __restrict__ cbT,
                                              u16* __restrict__ cbTh,
                                              float* __restrict__ negC0,
                                              u16* __restrict__ wh,
                                              u16* __restrict__ wm,
                                              u16* __restrict__ wl) {
    int bx = blockIdx.x, tid = threadIdx.x;
    if (bx < 2048) {
        __shared__ float tile[32][33];
        int k0 = (bx & 255) * 32, d0 = (bx >> 8) * 32;
        int tx = tid & 31, ty = tid >> 5;  // 32 x 8
#pragma unroll
        for (int i = 0; i < 4; i++) {
            int d = d0 + ty + i * 8;
            tile[ty + i * 8][tx] = cb[d * KK + k0 + tx];
        }
        __syncthreads();
#pragma unroll
        for (int i = 0; i < 4; i++) {
            int k = k0 + ty + i * 8;
            float v = tile[tx][ty + i * 8];
            cbT[k * DD + d0 + tx] = v;
            cbTh[k * DD + d0 + tx] = f2b(v);
        }
    } else if (bx < 2304) {
        __shared__ float sm[8][32];
        int kl = tid & 31, dg = tid >> 5;
        int k = (bx - 2048) * 32 + kl;
        float s = 0.f;
#pragma unroll
        for (int j = 0; j < 32; j++) {
            float v = cb[(size_t)(dg * 32 + j) * KK + k];
            s += v * v;
        }
        sm[dg][kl] = s;
        __syncthreads();
        if (tid < 32) {
            float t = 0.f;
#pragma unroll
            for (int g = 0; g < 8; g++) t += sm[g][tid];
            negC0[(bx - 2048) * 32 + tid] = -0.5f * (t + 1024.f);
        }
    } else {
        int t = (bx - 2304) * 256 + tid;
        u16 h, m, l; split3(Wm[t], h, m, l);
        wh[t] = h; wm[t] = m; wl[t] = l;
    }
}

// ---------------------------------------------------------------------------
// K1: xp = x_r @ W^T + b via bf16x3 split MFMA (6 terms ~ fp32 accuracy).
// R12: parallelism 2x — wave = 16 rows x 64 d (dt-quarter = wave id), block =
// 16 rows x 256 d, grid NN/16 = 1024 -> 4096 waves (4/SIMD, was 2/SIMD).
// R11 counters showed pure latency-bound (MfmaUtil 8.8, VALUBusy 8.3, occ
// 19.9% — grid-capped at 2 blocks/CU). Same per-lane fragment roles and
// numerics; acc 8->4 f32x4; x split3 redundancy x2->x4 (VALU was 8% busy).
__global__ __launch_bounds__(256) void k_proj(const float* __restrict__ x,
                                              const u16* __restrict__ wh,
                                              const u16* __restrict__ wm,
                                              const u16* __restrict__ wl,
                                              const float* __restrict__ bias,
                                              float* __restrict__ xp,
                                              u16* __restrict__ xpH) {
    int tid = threadIdx.x;
    int wave = tid >> 6, lane = tid & 63;    // wave = dt-quarter (0..3)
    int quad = lane >> 4, l15 = lane & 15;
    int n0 = blockIdx.x * 16;
    int n_a = n0 + l15;
    const float* xb = x + (n_a >> 10) * (CC * HW) + (n_a & (HW - 1));

    f32x4 acc[4];
#pragma unroll
    for (int i = 0; i < 4; i++) acc[i] = (f32x4){0.f, 0.f, 0.f, 0.f};

#pragma unroll
    for (int cc = 0; cc < 8; cc++) {
        bf16x8 ah, am, al;
#pragma unroll
        for (int j = 0; j < 8; j++) {
            float v = xb[(cc * 32 + quad * 8 + j) * HW];
            u16 h, m, l; split3(v, h, m, l);
            ah[j] = (short)h; am[j] = (short)m; al[j] = (short)l;
        }
#pragma unroll
        for (int dt = 0; dt < 4; dt++) {
            int dtg = wave * 4 + dt;
            int off = (dtg * 16 + l15) * CC + cc * 32 + quad * 8;
            const bf16x8 bh = *(const bf16x8*)(wh + off);
            const bf16x8 bm = *(const bf16x8*)(wm + off);
            const bf16x8 bl = *(const bf16x8*)(wl + off);
            acc[dt] = MFMA_BF16(ah, bh, acc[dt]);
            acc[dt] = MFMA_BF16(am, bh, acc[dt]);
            acc[dt] = MFMA_BF16(ah, bm, acc[dt]);
            acc[dt] = MFMA_BF16(al, bh, acc[dt]);
            acc[dt] = MFMA_BF16(am, bm, acc[dt]);
            acc[dt] = MFMA_BF16(ah, bl, acc[dt]);
        }
    }

#pragma unroll
    for (int dt = 0; dt < 4; dt++) {
        int d = (wave * 4 + dt) * 16 + l15;  // C-layout: col = lane&15
        float bv = bias[d];
#pragma unroll
        for (int r = 0; r < 4; r++) {
            int n = n0 + quad * 4 + r;       // C-layout: row = quad*4 + reg
            float v = acc[dt][r] + bv;
            xp[n * DD + d] = v;
            xpH[n * DD + d] = f2b(v);
        }
    }
}

// ---------------------------------------------------------------------------
// K2: approx distance GEMM (32x32x16 MFMA) + fused argmin-candidate select.
// Verified best structure (R1: 92.6 us): KROWS=32, XOR swizzle, 2 LDS
// buffers, __syncthreads per kc, mt=1, ILP-2 MFMA chains. Single dispatch.
// C/D (verified m74/m101): col = lane&31, row = (reg&3)+8*(reg>>2)+4*(lane>>5).
__global__ __launch_bounds__(256, 3) void k_dist(const u16* __restrict__ xpH,
                                                 const u16* __restrict__ cbTh,
                                                 const float* __restrict__ negC0,
                                                 u32* __restrict__ pkey) {
    __shared__ __align__(16) u16 tile[2][KROWS * 256];  // 2 x 16 KB
    int tid = threadIdx.x, wave = tid >> 6, lane = tid & 63;
    int col = lane & 31, half = lane >> 5;
    int n0 = blockIdx.x * 128 + wave * 32;
    int ksbase = blockIdx.y * (KK / KSPLIT);   // 512 codes per split

    // A-frags resident: 16 ks (row = col, dims ks*16 + half*8 + j)
    bf16x8 Ah[16];
    {
        const u16* ab = xpH + (size_t)(n0 + col) * DD + half * 8;
#pragma unroll
        for (int ks = 0; ks < 16; ks++)
            Ah[ks] = *(const bf16x8*)(ab + ks * 16);
    }

    u32 key[16];
#pragma unroll
    for (int g = 0; g < 16; g++) key[g] = 0xffffffffu;

#define STAGE(bufi, kglob_)                                                    \
    {                                                                          \
        int kg_ = (kglob_);                                                    \
        _Pragma("unroll")                                                      \
        for (int c = 0; c < 4; c++) {                                          \
            int chunk = wave * 4 + c;                                          \
            int row = chunk * 2 + (lane >> 5);                                 \
            int g = (lane & 31) ^ (row & 7);                                   \
            const u16* src = cbTh + (size_t)(kg_ + row) * DD + g * 8;          \
            async_load16(src, &tile[bufi][chunk * 512]);                       \
        }                                                                      \
    }

    STAGE(0, ksbase);
    float nc_cur = negC0[ksbase + col];
    __syncthreads();

    for (int kc = 0; kc < 16; kc++) {
        int buf = kc & 1;
        float nc_next = 0.f;
        if (kc < 15) {
            STAGE(buf ^ 1, ksbase + (kc + 1) * KROWS);
            nc_next = negC0[ksbase + (kc + 1) * KROWS + col];
        }

        f32x16 a0, a1;
#pragma unroll
        for (int g = 0; g < 16; g++) { a0[g] = nc_cur; a1[g] = 0.f; }

        const u16* trow = &tile[buf][col * 256];
#pragma unroll
        for (int ks = 0; ks < 8; ks++) {
            int g0 = ((2 * ks) * 2 + half) ^ (col & 7);
            int g1 = ((2 * ks + 1) * 2 + half) ^ (col & 7);
            const bf16x8 Bf0 = *(const bf16x8*)(trow + g0 * 8);
            const bf16x8 Bf1 = *(const bf16x8*)(trow + g1 * 8);
            a0 = MFMA32_BF16(Ah[2 * ks], Bf0, a0);
            a1 = MFMA32_BF16(Ah[2 * ks + 1], Bf1, a1);
        }

        u32 orv = ((u32)kc << 5) | (u32)col;
#pragma unroll
        for (int g = 0; g < 16; g++) {
            u32 kb = (f2u(a0[g] + a1[g]) & 0xFFFFFE00u) | orv;
            key[g] = min(key[g], kb);
        }
        nc_cur = nc_next;
        __syncthreads();  // drains prefetch + guards buffers
    }
#undef STAGE

    // top-2 across the 32 lanes (cols) sharing each C row
#pragma unroll
    for (int g = 0; g < 16; g++) {
        u32 k1 = key[g], k2 = 0xffffffffu;
#pragma unroll
        for (int m = 1; m < 32; m <<= 1) {
            u32 o1 = (u32)__shfl_xor((int)k1, m, 64);
            u32 o2 = (u32)__shfl_xor((int)k2, m, 64);
            u32 mx = max(k1, o1);
            k1 = min(k1, o1);
            k2 = min(min(k2, o2), mx);
        }
        if (col == 0) {
            int row = (g & 3) + 8 * (g >> 2) + 4 * half;
            int n = n0 + row;
            int base = (n * KSPLIT + blockIdx.y) * 2;
            pkey[base]     = (u32)ksbase + (k1 & 511u);
            pkey[base + 1] = (u32)ksbase + (k2 & 511u);
        }
    }
}

// ---------------------------------------------------------------------------
// K3: exact fp64 rescore of 32 candidates per row. One wave per row, 4 serial
// groups (verified best: 79 us — R8 ILP and R10 TLP variants both regressed;
// bound by scattered-request throughput). Single dispatch.
__global__ __launch_bounds__(256) void k_rescore(const float* __restrict__ xp,
                                                 const float* __restrict__ cbT,
                                                 const u32* __restrict__ pkey,
                                                 u32* __restrict__ idxv,
                                                 float* __restrict__ outIdx,
                                                 float* __restrict__ pmin) {
    int tid = threadIdx.x, wave = tid >> 6, lane = tid & 63;
    int n = blockIdx.x * 4 + wave;
    int sub = lane >> 3;
    int oct = lane & 7;

    f32x4 xv[8];
    const float* xb = xp + n * DD + oct * 32;
#pragma unroll
    for (int t = 0; t < 8; t++) xv[t] = *(const f32x4*)(xb + t * 4);

    u32 myk = pkey[n * 32 + (lane & 31)] & 8191u;

    double bestv = 1e300;
    u32 besti = 0u;
#pragma unroll
    for (int g = 0; g < 4; g++) {
        int c = g * 8 + sub;
        u32 kg = (u32)__shfl((int)myk, c, 64);
        const float* cv = cbT + kg * DD + oct * 32;
        double s = 0.0;
#pragma unroll
        for (int t = 0; t < 8; t++) {
            f32x4 cvv = *(const f32x4*)(cv + t * 4);
#pragma unroll
            for (int q = 0; q < 4; q++) {
                double d = (double)xv[t][q] - (double)cvv[q];
                s += d * d;
            }
        }
        s += __shfl_xor(s, 1, 64);
        s += __shfl_xor(s, 2, 64);
        s += __shfl_xor(s, 4, 64);
        if (s < bestv || (s == bestv && kg < besti)) { bestv = s; besti = kg; }
    }
#pragma unroll
    for (int m = 8; m < 64; m <<= 1) {
        double ov = __shfl_xor(bestv, m, 64);
        u32 oi = (u32)__shfl_xor((int)besti, m, 64);
        if (ov < bestv || (ov == bestv && oi < besti)) { bestv = ov; besti = oi; }
    }
    if (lane == 0) {
        idxv[n] = besti;
        outIdx[n] = (float)besti;
        pmin[n] = (float)bestv;
    }
}

// ---------------------------------------------------------------------------
// K4: diff = sum(pmin)/(N*D), fp64 (pmin in ws, no ordering constraint).
__global__ __launch_bounds__(1024) void k_final(const float* __restrict__ pmin,
                                                float* __restrict__ out) {
    __shared__ double sm[16];
    int tid = threadIdx.x, lane = tid & 63, wv = tid >> 6;
    double s = 0.0;
#pragma unroll
    for (int i = 0; i < 16; i++) s += (double)pmin[i * 1024 + tid];
#pragma unroll
    for (int m = 1; m < 64; m <<= 1) s += __shfl_xor(s, m, 64);
    if (lane == 0) sm[wv] = s;
    __syncthreads();
    if (tid == 0) {
        double t = 0.0;
#pragma unroll
        for (int i = 0; i < 16; i++) t += sm[i];
        out[0] = (float)(t * (1.0 / (double)OUT0));
    }
}

// ---------------------------------------------------------------------------
// K5: gather quantized (B,D,H,W) fp32 via LDS transpose tiles. Rewrites ALL
// of d_out chunk 0 (every scratch byte).
__global__ __launch_bounds__(256) void k_gather(const float* __restrict__ cbT,
                                                const u32* __restrict__ idxv,
                                                float* __restrict__ out0) {
    __shared__ float tile[32 * 260];
    int tid = threadIdx.x;
    int n0 = blockIdx.x * 32;
    int b = n0 >> 10, hw0 = n0 & 1023;

    {
        int r = tid >> 3, seg = tid & 7;
        u32 k = idxv[n0 + r] & 8191u;
        const float* src = cbT + k * DD + seg * 32;
        float* dst = tile + r * 260 + seg * 32;
#pragma unroll
        for (int j = 0; j < 8; j++)
            *(f32x4*)(dst + j * 4) = *(const f32x4*)(src + j * 4);
    }
    __syncthreads();
    {
        int hw = tid & 31, dq = tid >> 5;
        const float* trow = tile + hw * 260;
        float* obase = out0 + ((size_t)b * DD) * HW + hw0 + hw;
#pragma unroll
        for (int dj = 0; dj < 32; dj++) {
            int d = dq * 32 + dj;
            obase[(size_t)d * HW] = trow[d];
        }
    }
}

// ---------------------------------------------------------------------------
extern "C" void kernel_launch(void* const* d_in, const int* in_sizes, int n_in,
                              void* d_out, int out_size, void* d_ws, size_t ws_size,
                              hipStream_t stream) {
    const float* x = nullptr; const float* Wm = nullptr;
    const float* bias = nullptr; const float* cb = nullptr;
    for (int i = 0; i < n_in; i++) {
        switch (in_sizes[i]) {
            case 4194304: x    = (const float*)d_in[i]; break;  // (16,256,32,32)
            case 65536:   Wm   = (const float*)d_in[i]; break;  // (256,256)
            case 256:     bias = (const float*)d_in[i]; break;  // (256,)
            case 2097152: cb   = (const float*)d_in[i]; break;  // (256,8192)
        }
    }

    // d_out is FP32: [quantized (4194304) | diff (1) | indices (16384)]
    float* out0    = (float*)d_out;
    float* outDiff = (float*)d_out + OUT0;
    float* outIdx  = (float*)d_out + OUT0 + 1;

    // Transient scratch inside d_out chunk 0 (16.78 MB; every byte rewritten
    // by k_gather before the harness reads):
    char* o = (char*)d_out;
    u16*   cbTh = (u16*)o;                       // [0, 4 MB)
    u32*   pkey = (u32*)(o + 4194304);           // [4 MB, 6 MB)
    u16*   wh   = (u16*)(o + 6291456);           // 128 KB
    u16*   wm   = (u16*)(o + 6422528);           // 128 KB
    u16*   wl   = (u16*)(o + 6553600);           // 128 KB
    u16*   xpH  = (u16*)(o + 6750208);           // 8 MB  (N,D) bf16 -> ends 14.75 MB

    // Workspace (~25.33 MB, footprint that passed in rounds 4-9):
    char* w = (char*)d_ws;
    float* cbT   = (float*)(w);                  // 8 MB  (K,D) fp32
    float* xp    = (float*)(w + 8388608);        // 16 MB (N,D) fp32
    float* negC0 = (float*)(w + 25165824);       // 32 KB
    u32*   idxv  = (u32*)(w + 25198592);         // 64 KB
    float* pmin  = (float*)(w + 25264128);       // 64 KB

    k_prep<<<2560, 256, 0, stream>>>(cb, Wm, cbT, cbTh, negC0, wh, wm, wl);
    k_proj<<<NN / 16, 256, 0, stream>>>(x, wh, wm, wl, bias, xp, xpH);
    k_dist<<<dim3(NN / 128, KSPLIT), 256, 0, stream>>>(xpH, cbTh, negC0, pkey);
    k_rescore<<<NN / 4, 256, 0, stream>>>(xp, cbT, pkey, idxv, outIdx, pmin);
    k_final<<<1, 1024, 0, stream>>>(pmin, outDiff);
    k_gather<<<NN / 32, 256, 0, stream>>>(cbT, idxv, out0);
}